// Round 2
// baseline (228.176 us; speedup 1.0000x reference)
//
#include <hip/hip_runtime.h>

typedef unsigned int u32;
typedef float v2f __attribute__((ext_vector_type(2)));

#define DIM 16384
#define NT  512

// Swizzle v3 (HW-validated R4): s1=y1^y4, s2=y2^y7, s3=y3^y6^y8. Conflict-free
// under the 8-lane(b128)/16-lane(b64) phase model for all pass patterns.
__host__ __device__ constexpr u32 swz0(u32 d) {
    u32 b1 = (d >> 4) & 1u;
    u32 b2 = (d >> 7) & 1u;
    u32 b3 = ((d >> 6) ^ (d >> 8)) & 1u;
    return d ^ (b1 << 1) ^ (b2 << 2) ^ (b3 << 3);
}

// CNOT-ring basis map (HW-validated R2/R3): GF(2)-linear.
__host__ __device__ constexpr u32 mmap(u32 y) {
    u32 s = y;
    s ^= s >> 1; s ^= s >> 2; s ^= s >> 4; s ^= s >> 8;
    return (s & 0x1FFFu) | (((s ^ (y >> 13)) & 1u) << 13);
}

__device__ __forceinline__ v2f mkv2(float x, float y) { v2f t; t.x = x; t.y = y; return t; }

// VOP3P packed f32. NOTE (model correction R1): gfx950 FP32 peak = 1 FMA/lane/cyc,
// so packing does NOT double FLOP rate — it halves instruction count/fetch and
// shortens dep chains. The real lever this round is the 2-state interleave below.
__device__ __forceinline__ v2f pk_mul(v2f a, v2f b) {
    v2f d;
    asm("v_pk_mul_f32 %0, %1, %2" : "=v"(d) : "v"(a), "v"(b));
    return d;
}
__device__ __forceinline__ v2f pk_fma(v2f a, v2f b, v2f c) {
    v2f d;
    asm("v_pk_fma_f32 %0, %1, %2, %3" : "=v"(d) : "v"(a), "v"(b), "v"(c));
    return d;
}

// amp = (re,im) in one VGPR pair. Bitwise-identical rounding to the scalar
// version: n0 = fma(c,a0, (-s)*a1), n1 = fma(c,a1, s*a0).
__device__ __forceinline__ void rot2(v2f& a0, v2f& a1, v2f cc, v2f ss, v2f ns) {
    v2f t1 = pk_mul(ss, a0);
    v2f t0 = pk_mul(ns, a1);
    a0 = pk_fma(cc, a0, t0);
    a1 = pk_fma(cc, a1, t1);
}

template<int D>
__device__ __forceinline__ void gate32(v2f (&am)[32], float c, float s) {
    v2f cc = {c, c}, ss = {s, s}, ns = {-s, -s};
    #pragma unroll
    for (int r = 0; r < 32; ++r) if (!(r & D)) rot2(am[r], am[r | D], cc, ss, ns);
}

// ---- pass A: register bits {y0,y1,y11,y12,y13}, thread bits y2..y10 ----
__device__ __forceinline__ void rdA(int tid, float* smem, v2f (&am)[32]) {
    float4* stv = (float4*)smem;
    u32 sbase = swz0((u32)tid << 2);
    #pragma unroll
    for (int h = 0; h < 8; ++h)
        #pragma unroll
        for (int m = 0; m < 2; ++m) {
            u32 idx = (sbase ^ swz0(((u32)h << 11) | ((u32)m << 1))) >> 1;
            float4 v = stv[idx];
            int r = h * 4 + m * 2;
            am[r]     = mkv2(v.x, v.y);
            am[r + 1] = mkv2(v.z, v.w);
        }
}
__device__ __forceinline__ void wrA(int tid, float* smem, v2f (&am)[32]) {
    float4* stv = (float4*)smem;
    u32 sbase = swz0((u32)tid << 2);
    #pragma unroll
    for (int h = 0; h < 8; ++h)
        #pragma unroll
        for (int m = 0; m < 2; ++m) {
            u32 idx = (sbase ^ swz0(((u32)h << 11) | ((u32)m << 1))) >> 1;
            int r = h * 4 + m * 2;
            stv[idx] = make_float4(am[r].x, am[r].y, am[r + 1].x, am[r + 1].y);
        }
}
template<int L>
__device__ __forceinline__ void gatesA(const float* angC, const float* angS, v2f (&am)[32]) {
    gate32< 1>(am, angC[L * 16 +  0], angS[L * 16 +  0]);  // y0
    gate32< 2>(am, angC[L * 16 +  1], angS[L * 16 +  1]);  // y1
    gate32< 4>(am, angC[L * 16 + 11], angS[L * 16 + 11]);  // y11
    gate32< 8>(am, angC[L * 16 + 12], angS[L * 16 + 12]);  // y12
    gate32<16>(am, angC[L * 16 + 13], angS[L * 16 + 13]);  // y13
}

// ---- pass B: register bits {y6..y10} ----
__device__ __forceinline__ void rdB(int tid, float* smem, v2f (&am)[32]) {
    v2f* st2 = (v2f*)smem;
    u32 ybase = ((u32)tid & 63u) | (((u32)tid >> 6) << 11);
    u32 sbase = swz0(ybase);
    #pragma unroll
    for (int j = 0; j < 32; ++j) am[j] = st2[sbase ^ swz0((u32)j << 6)];
}
__device__ __forceinline__ void wrB(int tid, float* smem, v2f (&am)[32]) {
    v2f* st2 = (v2f*)smem;
    u32 ybase = ((u32)tid & 63u) | (((u32)tid >> 6) << 11);
    u32 sbase = swz0(ybase);
    #pragma unroll
    for (int j = 0; j < 32; ++j) st2[sbase ^ swz0((u32)j << 6)] = am[j];
}
template<int L>
__device__ __forceinline__ void gatesB(const float* angC, const float* angS, v2f (&am)[32]) {
    gate32< 1>(am, angC[L * 16 +  6], angS[L * 16 +  6]);
    gate32< 2>(am, angC[L * 16 +  7], angS[L * 16 +  7]);
    gate32< 4>(am, angC[L * 16 +  8], angS[L * 16 +  8]);
    gate32< 8>(am, angC[L * 16 +  9], angS[L * 16 +  9]);
    gate32<16>(am, angC[L * 16 + 10], angS[L * 16 + 10]);
}

// ---- pass C: register bits {y0,y2,y3,y4,y5}; scatter applies CNOT-ring mmap ----
__device__ __forceinline__ void rdC(int tid, float* smem, v2f (&am)[32]) {
    float4* stv = (float4*)smem;
    u32 ybase = (((u32)tid & 1u) << 1) | (((u32)tid >> 1) << 6);
    u32 sbase = swz0(ybase);
    #pragma unroll
    for (int h = 0; h < 16; ++h) {
        u32 idx = (sbase ^ swz0((u32)h << 2)) >> 1;
        float4 v = stv[idx];
        am[h * 2]     = mkv2(v.x, v.y);
        am[h * 2 + 1] = mkv2(v.z, v.w);
    }
}
__device__ __forceinline__ void wrCs(int tid, float* smem, v2f (&am)[32]) {
    v2f* st2 = (v2f*)smem;
    u32 ybase = (((u32)tid & 1u) << 1) | (((u32)tid >> 1) << 6);
    u32 pbase = swz0(mmap(ybase));
    #pragma unroll
    for (int h = 0; h < 16; ++h)
        #pragma unroll
        for (int q = 0; q < 2; ++q) {
            u32 slot = pbase ^ swz0(mmap(((u32)h << 2) | (u32)q));
            st2[slot] = am[h * 2 + q];
        }
}
template<int L>
__device__ __forceinline__ void gatesC(const float* angC, const float* angS, v2f (&am)[32]) {
    gate32< 2>(am, angC[L * 16 + 2], angS[L * 16 + 2]);  // y2
    gate32< 4>(am, angC[L * 16 + 3], angS[L * 16 + 3]);
    gate32< 8>(am, angC[L * 16 + 4], angS[L * 16 + 4]);
    gate32<16>(am, angC[L * 16 + 5], angS[L * 16 + 5]);
}
__device__ __forceinline__ void measC(int tid, const float* lutLo, const float* lutHi,
                                      v2f (&am)[32], float& acc, float W0) {
    u32 ybase = (((u32)tid & 1u) << 1) | (((u32)tid >> 1) << 6);
    u32 myb = mmap(ybase);
    #pragma unroll
    for (int h = 0; h < 16; ++h)
        #pragma unroll
        for (int q = 0; q < 2; ++q) {
            u32 yp = myb ^ mmap(((u32)h << 2) | (u32)q);
            int r = h * 2 + q;
            float p  = fmaf(am[r].x, am[r].x, am[r].y * am[r].y);
            float wv = W0 - 2.0f * (lutLo[yp & 127u] + lutHi[yp >> 7]);
            acc = fmaf(wv, p, acc);
        }
}

// Two states per block, single 128KB LDS buffer time-shared. Every exchange is
// write(S) -> sync -> read(S) -> [gates on OTHER state hide read latency +
// stagger barrier arrival] -> sync. Full-drain barriers between every buffer
// write phase and read phase: race-free by construction.
__global__ __launch_bounds__(NT, 2) void qsim_kernel(
    const float* __restrict__ sreal, const float* __restrict__ simag,
    const float* __restrict__ wts,   const float* __restrict__ hw,
    const float* __restrict__ hb,    float* __restrict__ out, int batch)
{
    extern __shared__ float smem[];
    float* angC   = smem + 32768;
    float* angS   = angC + 48;
    float* lutLo  = angS + 48;
    float* lutHi  = lutLo + 128;
    float* redbuf = lutHi + 128;

    int tid = threadIdx.x;
    int b0  = blockIdx.x * 2;
    int b1  = (b0 + 1 < batch) ? b0 + 1 : b0;   // odd-batch guard: duplicate, skip store

    v2f am[32], bm[32];

    // state X global load (A-layout): float4 (h<<9)|tid covers y=(h<<11)|(tid<<2)|{0..3}
    {
        const float4* pr = (const float4*)(sreal + (size_t)b0 * DIM);
        const float4* pi = (const float4*)(simag + (size_t)b0 * DIM);
        #pragma unroll
        for (int h = 0; h < 8; ++h) {
            float4 r = pr[(h << 9) | tid];
            float4 i = pi[(h << 9) | tid];
            am[h * 4 + 0] = mkv2(r.x, i.x);
            am[h * 4 + 1] = mkv2(r.y, i.y);
            am[h * 4 + 2] = mkv2(r.z, i.z);
            am[h * 4 + 3] = mkv2(r.w, i.w);
        }
    }

    // block-uniform setup: summed half-angles (3 RYs/wire/layer compose) + head LUTs
    if (tid < 42) {
        int l = tid / 14, bb = tid % 14, q = 13 - bb;   // bit bb <-> wire 13-bb
        float a = 0.5f * (wts[l * 42 + q] + wts[l * 42 + 14 + q] + wts[l * 42 + 28 + q]);
        angC[l * 16 + bb] = cosf(a);
        angS[l * 16 + bb] = sinf(a);
    } else if (tid >= 64 && tid < 192) {
        int i = tid - 64;           // low 7 index bits -> wires 13..7
        float ssum = 0.f;
        for (int bb = 0; bb < 7; ++bb) if ((i >> bb) & 1) ssum += hw[13 - bb];
        lutLo[i] = ssum;
    } else if (tid >= 192 && tid < 320) {
        int i = tid - 192;          // high 7 index bits -> wires 6..0
        float ssum = 0.f;
        for (int bb = 0; bb < 7; ++bb) if ((i >> bb) & 1) ssum += hw[6 - bb];
        lutHi[i] = ssum;
    }

    // state Y global load (issued after libm setup to cap register peak;
    // latency hidden under X's first gate set + exchange)
    {
        const float4* pr = (const float4*)(sreal + (size_t)b1 * DIM);
        const float4* pi = (const float4*)(simag + (size_t)b1 * DIM);
        #pragma unroll
        for (int h = 0; h < 8; ++h) {
            float4 r = pr[(h << 9) | tid];
            float4 i = pi[(h << 9) | tid];
            bm[h * 4 + 0] = mkv2(r.x, i.x);
            bm[h * 4 + 1] = mkv2(r.y, i.y);
            bm[h * 4 + 2] = mkv2(r.z, i.z);
            bm[h * 4 + 3] = mkv2(r.w, i.w);
        }
    }

    __syncthreads();
    float W0   = lutLo[127] + lutHi[127];   // sum of all head weights
    float accX = 0.f, accY = 0.f;

    #define SYNC __syncthreads()

    // ---- layer 0 ----
    gatesA<0>(angC, angS, am);
    wrA(tid, smem, am);                              SYNC;
    rdB(tid, smem, am);  gatesA<0>(angC, angS, bm);  SYNC;
    wrA(tid, smem, bm);                              SYNC;
    rdB(tid, smem, bm);  gatesB<0>(angC, angS, am);  SYNC;
    wrB(tid, smem, am);                              SYNC;
    rdC(tid, smem, am);  gatesB<0>(angC, angS, bm);  SYNC;
    wrB(tid, smem, bm);                              SYNC;
    rdC(tid, smem, bm);  gatesC<0>(angC, angS, am);  SYNC;
    wrCs(tid, smem, am);                             SYNC;
    rdA(tid, smem, am);  gatesC<0>(angC, angS, bm);  SYNC;
    wrCs(tid, smem, bm);                             SYNC;
    // ---- layer 1 ----
    rdA(tid, smem, bm);  gatesA<1>(angC, angS, am);  SYNC;
    wrA(tid, smem, am);                              SYNC;
    rdB(tid, smem, am);  gatesA<1>(angC, angS, bm);  SYNC;
    wrA(tid, smem, bm);                              SYNC;
    rdB(tid, smem, bm);  gatesB<1>(angC, angS, am);  SYNC;
    wrB(tid, smem, am);                              SYNC;
    rdC(tid, smem, am);  gatesB<1>(angC, angS, bm);  SYNC;
    wrB(tid, smem, bm);                              SYNC;
    rdC(tid, smem, bm);  gatesC<1>(angC, angS, am);  SYNC;
    wrCs(tid, smem, am);                             SYNC;
    rdA(tid, smem, am);  gatesC<1>(angC, angS, bm);  SYNC;
    wrCs(tid, smem, bm);                             SYNC;
    // ---- layer 2 (measurement fused, no final scatter) ----
    rdA(tid, smem, bm);  gatesA<2>(angC, angS, am);  SYNC;
    wrA(tid, smem, am);                              SYNC;
    rdB(tid, smem, am);  gatesA<2>(angC, angS, bm);  SYNC;
    wrA(tid, smem, bm);                              SYNC;
    rdB(tid, smem, bm);  gatesB<2>(angC, angS, am);  SYNC;
    wrB(tid, smem, am);                              SYNC;
    rdC(tid, smem, am);  gatesB<2>(angC, angS, bm);  SYNC;
    wrB(tid, smem, bm);                              SYNC;
    rdC(tid, smem, bm);
    gatesC<2>(angC, angS, am);  measC(tid, lutLo, lutHi, am, accX, W0);
    gatesC<2>(angC, angS, bm);  measC(tid, lutLo, lutHi, bm, accY, W0);

    #undef SYNC

    // block reduction (both states)
    #pragma unroll
    for (int off = 32; off > 0; off >>= 1) {
        accX += __shfl_xor(accX, off, 64);
        accY += __shfl_xor(accY, off, 64);
    }
    if ((tid & 63) == 0) {
        redbuf[tid >> 6]     = accX;
        redbuf[8 + (tid >> 6)] = accY;
    }
    __syncthreads();
    if (tid == 0) {
        float tx = hb[0], ty = hb[0];
        #pragma unroll
        for (int i = 0; i < 8; ++i) { tx += redbuf[i]; ty += redbuf[8 + i]; }
        out[b0] = tx;
        if (b0 + 1 < batch) out[b0 + 1] = ty;
    }
}

extern "C" void kernel_launch(void* const* d_in, const int* in_sizes, int n_in,
                              void* d_out, int out_size, void* d_ws, size_t ws_size,
                              hipStream_t stream)
{
    const float* sreal = (const float*)d_in[0];
    const float* simag = (const float*)d_in[1];
    const float* wts   = (const float*)d_in[2];
    const float* hw    = (const float*)d_in[3];
    const float* hb    = (const float*)d_in[4];
    float* out = (float*)d_out;

    int batch  = in_sizes[0] / DIM;
    int nblk   = (batch + 1) / 2;
    size_t smem_bytes = (32768 + 48 + 48 + 128 + 128 + 16) * sizeof(float);  // ~129.4 KiB < 160 KiB

    (void)hipFuncSetAttribute((const void*)qsim_kernel,
                              hipFuncAttributeMaxDynamicSharedMemorySize, (int)smem_bytes);
    qsim_kernel<<<dim3(nblk), dim3(NT), smem_bytes, stream>>>(sreal, simag, wts, hw, hb, out, batch);
}

// Round 3
// 217.770 us; speedup vs baseline: 1.0478x; 1.0478x over previous
//
#include <hip/hip_runtime.h>

typedef unsigned int u32;

#define DIM 16384
#define NT  512

// Swizzle v4 (R3): s0=y0^y4^y5, s1=y1^y4, s2=y2^y7^y8, s3=y3^y6^y8.
// Chosen so ALL nine LDS access patterns {A,B,C} x {imap^0, imap^1, imap^2}
// are bank-conflict-free under the 8-lane(b128)/16-lane(b64) phase model
// (full-rank lane->bank-nibble maps, verified by hand per pattern).
__host__ __device__ constexpr u32 swzN(u32 d) {
    u32 b0 = ((d >> 4) ^ (d >> 5)) & 1u;
    u32 b1 = (d >> 4) & 1u;
    u32 b2 = ((d >> 7) ^ (d >> 8)) & 1u;
    u32 b3 = ((d >> 6) ^ (d >> 8)) & 1u;
    return d ^ b0 ^ (b1 << 1) ^ (b2 << 2) ^ (b3 << 3);
}

// CNOT-ring basis map (HW-validated R2/R3): M(y)_b = XOR_{p>=b} y_p (b<=12),
// M(y)_13 = XOR_{p<=12} y_p. GF(2)-linear.
__host__ __device__ constexpr u32 mmap(u32 y) {
    u32 s = y;
    s ^= s >> 1; s ^= s >> 2; s ^= s >> 4; s ^= s >> 8;
    return (s & 0x1FFFu) | (((s ^ (y >> 13)) & 1u) << 13);
}

// Inverse ring map M^-1: y_b = z_b ^ z_{b+1} (b<=11); y13 = z0^z13; y12 = z12^y13.
// Verified: imap1(mmap(y)) == y for the encoding above.
__host__ __device__ constexpr u32 imap1(u32 z) {
    u32 lo  = (z ^ (z >> 1)) & 0x0FFFu;
    u32 y13 = (z ^ (z >> 13)) & 1u;
    u32 y12 = ((z >> 12) & 1u) ^ y13;
    return lo | (y12 << 12) | (y13 << 13);
}

// Deferred-basis slot function: at layer L the physical layout is L ring-maps
// behind the logical basis, so every access gathers via swzN(imap^L(z)).
// No scatter pass exists anymore; layer 2's final ring is folded into measC.
template<int L>
__host__ __device__ constexpr u32 sig(u32 y) {
    if constexpr (L == 0) return swzN(y);
    else if constexpr (L == 1) return swzN(imap1(y));
    else return swzN(imap1(imap1(y)));
}

// Scalar rotation (proven R0 codegen): n0 = fma(c,a0,-(s*a1)), n1 = fma(c,a1,s*a0).
__device__ __forceinline__ void rot2(float2& a0, float2& a1, float c, float s) {
    float t0x = s * a1.x, t0y = s * a1.y;
    float t1x = s * a0.x, t1y = s * a0.y;
    float n0x = fmaf(c, a0.x, -t0x), n0y = fmaf(c, a0.y, -t0y);
    float n1x = fmaf(c, a1.x,  t1x), n1y = fmaf(c, a1.y,  t1y);
    a0.x = n0x; a0.y = n0y;
    a1.x = n1x; a1.y = n1y;
}

template<int D>
__device__ __forceinline__ void gate32(float2 (&am)[32], float c, float s) {
    #pragma unroll
    for (int r = 0; r < 32; ++r) if (!(r & D)) rot2(am[r], am[r | D], c, s);
}

// ---- pass A: register bits {y0,y1,y11,y12,y13}; thread bits y2..y10 ----
template<int L>
__device__ __forceinline__ void passA(int tid, float* smem, float2 (&am)[32]) {
    float2* st2 = (float2*)smem;
    const float* angC = smem + 32768;
    const float* angS = smem + 32768 + 48;
    if (L > 0) {
        u32 base = sig<L>((u32)tid << 2);
        #pragma unroll
        for (int h = 0; h < 8; ++h)
            #pragma unroll
            for (int m = 0; m < 2; ++m)
                #pragma unroll
                for (int q = 0; q < 2; ++q)
                    am[h * 4 + m * 2 + q] =
                        st2[base ^ sig<L>(((u32)h << 11) | ((u32)m << 1) | (u32)q)];
    }
    gate32< 1>(am, angC[L * 16 +  0], angS[L * 16 +  0]);  // y0
    gate32< 2>(am, angC[L * 16 +  1], angS[L * 16 +  1]);  // y1
    gate32< 4>(am, angC[L * 16 + 11], angS[L * 16 + 11]);  // y11
    gate32< 8>(am, angC[L * 16 + 12], angS[L * 16 + 12]);  // y12
    gate32<16>(am, angC[L * 16 + 13], angS[L * 16 + 13]);  // y13
    if (L == 0) {
        // b128 write; pair order in the f4 flips with s0's base taps y4^y5 = t2^t3
        float4* stv = (float4*)smem;
        u32 base = swzN((u32)tid << 2);
        bool sw = (((tid >> 2) ^ (tid >> 3)) & 1) != 0;
        #pragma unroll
        for (int h = 0; h < 8; ++h)
            #pragma unroll
            for (int m = 0; m < 2; ++m) {
                u32 idx = (base ^ swzN(((u32)h << 11) | ((u32)m << 1))) >> 1;
                int r = h * 4 + m * 2;
                float2 a0 = am[r], a1 = am[r + 1];      // static indices only
                float4 v = sw ? make_float4(a1.x, a1.y, a0.x, a0.y)
                              : make_float4(a0.x, a0.y, a1.x, a1.y);
                stv[idx] = v;
            }
    } else {
        u32 base = sig<L>((u32)tid << 2);
        #pragma unroll
        for (int h = 0; h < 8; ++h)
            #pragma unroll
            for (int m = 0; m < 2; ++m)
                #pragma unroll
                for (int q = 0; q < 2; ++q)
                    st2[base ^ sig<L>(((u32)h << 11) | ((u32)m << 1) | (u32)q)] =
                        am[h * 4 + m * 2 + q];
    }
    __syncthreads();
}

// ---- pass B: register bits {y6..y10}; thread bits y0..y5,y11..y13 ----
template<int L>
__device__ __forceinline__ void passB(int tid, float* smem, float2 (&am)[32]) {
    float2* st2 = (float2*)smem;
    const float* angC = smem + 32768;
    const float* angS = smem + 32768 + 48;
    u32 ybase = ((u32)tid & 63u) | (((u32)tid >> 6) << 11);
    u32 base = sig<L>(ybase);
    #pragma unroll
    for (int j = 0; j < 32; ++j) am[j] = st2[base ^ sig<L>((u32)j << 6)];
    gate32< 1>(am, angC[L * 16 +  6], angS[L * 16 +  6]);
    gate32< 2>(am, angC[L * 16 +  7], angS[L * 16 +  7]);
    gate32< 4>(am, angC[L * 16 +  8], angS[L * 16 +  8]);
    gate32< 8>(am, angC[L * 16 +  9], angS[L * 16 +  9]);
    gate32<16>(am, angC[L * 16 + 10], angS[L * 16 + 10]);
    #pragma unroll
    for (int j = 0; j < 32; ++j) st2[base ^ sig<L>((u32)j << 6)] = am[j];
    __syncthreads();
}

// ---- pass C: register bits {y0,y2..y5}; thread bits y1,y6..y13 ----
// No scatter: write back to the SAME slots; the ring map is applied by the
// next layer's gather (L<2) or inside measC's weight indexing (L==2).
template<int L>
__device__ __forceinline__ void passC(int tid, float* smem, float2 (&am)[32],
                                      float& acc, float W0) {
    float2* st2 = (float2*)smem;
    float4* stv = (float4*)smem;
    const float* angC  = smem + 32768;
    const float* angS  = smem + 32768 + 48;
    const float* lutLo = smem + 32768 + 96;
    const float* lutHi = smem + 32768 + 96 + 128;
    u32 ybase = (((u32)tid & 1u) << 1) | (((u32)tid >> 1) << 6);
    if (L == 0) {
        u32 base = swzN(ybase);
        #pragma unroll
        for (int h = 0; h < 16; ++h) {
            u32 idx = (base ^ swzN((u32)h << 2)) >> 1;
            float4 v = stv[idx];
            if (((h >> 2) ^ (h >> 3)) & 1) {   // static swap: s0 taps y4^y5 = h2^h3
                am[h * 2 + 1] = make_float2(v.x, v.y);
                am[h * 2]     = make_float2(v.z, v.w);
            } else {
                am[h * 2]     = make_float2(v.x, v.y);
                am[h * 2 + 1] = make_float2(v.z, v.w);
            }
        }
    } else {
        u32 base = sig<L>(ybase);
        #pragma unroll
        for (int h = 0; h < 16; ++h)
            #pragma unroll
            for (int q = 0; q < 2; ++q)
                am[h * 2 + q] = st2[base ^ sig<L>(((u32)h << 2) | (u32)q)];
    }
    gate32< 2>(am, angC[L * 16 + 2], angS[L * 16 + 2]);  // y2
    gate32< 4>(am, angC[L * 16 + 3], angS[L * 16 + 3]);
    gate32< 8>(am, angC[L * 16 + 4], angS[L * 16 + 4]);
    gate32<16>(am, angC[L * 16 + 5], angS[L * 16 + 5]);
    if (L < 2) {
        if (L == 0) {
            u32 base = swzN(ybase);
            #pragma unroll
            for (int h = 0; h < 16; ++h) {
                u32 idx = (base ^ swzN((u32)h << 2)) >> 1;
                float2 a0 = am[h * 2], a1 = am[h * 2 + 1];
                if (((h >> 2) ^ (h >> 3)) & 1)
                    stv[idx] = make_float4(a1.x, a1.y, a0.x, a0.y);
                else
                    stv[idx] = make_float4(a0.x, a0.y, a1.x, a1.y);
            }
        } else {
            u32 base = sig<L>(ybase);
            #pragma unroll
            for (int h = 0; h < 16; ++h)
                #pragma unroll
                for (int q = 0; q < 2; ++q)
                    st2[base ^ sig<L>(((u32)h << 2) | (u32)q)] = am[h * 2 + q];
        }
        __syncthreads();
    } else {
        u32 myb = mmap(ybase);
        #pragma unroll
        for (int h = 0; h < 16; ++h)
            #pragma unroll
            for (int q = 0; q < 2; ++q) {
                u32 yp = myb ^ mmap(((u32)h << 2) | (u32)q);
                int r = h * 2 + q;
                float p  = fmaf(am[r].x, am[r].x, am[r].y * am[r].y);
                float wv = W0 - 2.0f * (lutLo[yp & 127u] + lutHi[yp >> 7]);
                acc = fmaf(wv, p, acc);
            }
    }
}

__global__ __launch_bounds__(NT, 2) void qsim_kernel(
    const float* __restrict__ sreal, const float* __restrict__ simag,
    const float* __restrict__ wts,   const float* __restrict__ hw,
    const float* __restrict__ hb,    float* __restrict__ out)
{
    extern __shared__ float smem[];
    float* angC   = smem + 32768;
    float* angS   = angC + 48;
    float* lutLo  = angS + 48;
    float* lutHi  = lutLo + 128;
    float* redbuf = lutHi + 128;

    int tid = threadIdx.x;
    int b   = blockIdx.x;

    // global load, A-layout: float4 (h<<9)|tid covers y = (h<<11)|(tid<<2)|{0..3}
    const float4* pr = (const float4*)(sreal + (size_t)b * DIM);
    const float4* pi = (const float4*)(simag + (size_t)b * DIM);
    float4 vr[8], vi[8];
    #pragma unroll
    for (int h = 0; h < 8; ++h) {
        vr[h] = pr[(h << 9) | tid];
        vi[h] = pi[(h << 9) | tid];
    }

    // block-uniform setup: summed half-angles (3 RYs/wire/layer compose) + head LUTs
    if (tid < 42) {
        int l = tid / 14, bb = tid % 14, q = 13 - bb;   // bit bb <-> wire 13-bb
        float a = 0.5f * (wts[l * 42 + q] + wts[l * 42 + 14 + q] + wts[l * 42 + 28 + q]);
        angC[l * 16 + bb] = cosf(a);
        angS[l * 16 + bb] = sinf(a);
    } else if (tid >= 64 && tid < 192) {
        int i = tid - 64;           // low 7 index bits -> wires 13..7
        float ssum = 0.f;
        for (int bb = 0; bb < 7; ++bb) if ((i >> bb) & 1) ssum += hw[13 - bb];
        lutLo[i] = ssum;
    } else if (tid >= 192 && tid < 320) {
        int i = tid - 192;          // high 7 index bits -> wires 6..0
        float ssum = 0.f;
        for (int bb = 0; bb < 7; ++bb) if ((i >> bb) & 1) ssum += hw[6 - bb];
        lutHi[i] = ssum;
    }

    float2 am[32];
    #pragma unroll
    for (int h = 0; h < 8; ++h) {
        am[h * 4 + 0] = make_float2(vr[h].x, vi[h].x);
        am[h * 4 + 1] = make_float2(vr[h].y, vi[h].y);
        am[h * 4 + 2] = make_float2(vr[h].z, vi[h].z);
        am[h * 4 + 3] = make_float2(vr[h].w, vi[h].w);
    }

    __syncthreads();
    float W0  = lutLo[127] + lutHi[127];   // sum of all head weights
    float acc = 0.f;

    passA<0>(tid, smem, am);
    passB<0>(tid, smem, am);
    passC<0>(tid, smem, am, acc, W0);
    passA<1>(tid, smem, am);
    passB<1>(tid, smem, am);
    passC<1>(tid, smem, am, acc, W0);
    passA<2>(tid, smem, am);
    passB<2>(tid, smem, am);
    passC<2>(tid, smem, am, acc, W0);

    // block reduction
    #pragma unroll
    for (int off = 32; off > 0; off >>= 1) acc += __shfl_xor(acc, off, 64);
    if ((tid & 63) == 0) redbuf[tid >> 6] = acc;
    __syncthreads();
    if (tid == 0) {
        float tot = hb[0];
        #pragma unroll
        for (int i = 0; i < 8; ++i) tot += redbuf[i];
        out[b] = tot;
    }
}

extern "C" void kernel_launch(void* const* d_in, const int* in_sizes, int n_in,
                              void* d_out, int out_size, void* d_ws, size_t ws_size,
                              hipStream_t stream)
{
    const float* sreal = (const float*)d_in[0];
    const float* simag = (const float*)d_in[1];
    const float* wts   = (const float*)d_in[2];
    const float* hw    = (const float*)d_in[3];
    const float* hb    = (const float*)d_in[4];
    float* out = (float*)d_out;

    int batch = in_sizes[0] / DIM;
    size_t smem_bytes = (32768 + 48 + 48 + 128 + 128 + 16) * sizeof(float);  // 132.5 KB < 160 KB

    (void)hipFuncSetAttribute((const void*)qsim_kernel,
                              hipFuncAttributeMaxDynamicSharedMemorySize, (int)smem_bytes);
    qsim_kernel<<<dim3(batch), dim3(NT), smem_bytes, stream>>>(sreal, simag, wts, hw, hb, out);
}

// Round 4
// 208.935 us; speedup vs baseline: 1.0921x; 1.0423x over previous
//
#include <hip/hip_runtime.h>

typedef unsigned int u32;

#define DIM 16384
#define NT  512

// Swizzle v4: s0=y0^y4^y5, s1=y1^y4, s2=y2^y7^y8, s3=y3^y6^y8. (R3-verified
// machinery; R3 falsified the conflict theory — counter == DS-instr floor —
// so the swizzle is kept unchanged and conflicts are ignored as a lever.)
__host__ __device__ constexpr u32 swzN(u32 d) {
    u32 b0 = ((d >> 4) ^ (d >> 5)) & 1u;
    u32 b1 = (d >> 4) & 1u;
    u32 b2 = ((d >> 7) ^ (d >> 8)) & 1u;
    u32 b3 = ((d >> 6) ^ (d >> 8)) & 1u;
    return d ^ b0 ^ (b1 << 1) ^ (b2 << 2) ^ (b3 << 3);
}

// CNOT-ring basis map (HW-validated): bits 0..12 = XOR_{p>=b} y_p, bit13 = XOR_{p<=12} y_p.
__host__ __device__ constexpr u32 mmap(u32 y) {
    u32 s = y;
    s ^= s >> 1; s ^= s >> 2; s ^= s >> 4; s ^= s >> 8;
    return (s & 0x1FFFu) | (((s ^ (y >> 13)) & 1u) << 13);
}

__host__ __device__ constexpr u32 mpow(u32 x, int L) {
    for (int i = 0; i < L; ++i) x = mmap(x);
    return x;
}

// ---- 7-pass schedule: physical stride subspaces (register bit i <-> PV[i]) ----
// Physical slot of amp p is swzN(p); amplitude of layer-L logical y sits at
// p = imap^L(y), so a gate (L, wire b) is a butterfly with stride imap^L(e_b).
// P1: L0 {0,1,11,12,13}  V={e0,e1,e11,e12,e13}   (global->reg, b128 write)
// P2: L0 {2,3,4,5}       V={e0,e2,e3,e4,e5}      (b128 r/w)
// P3: L0 {6..10} + L1 {7..10}   V={e6..e10}
// P4: L1 {2..6}          V={e1+e2,..,e5+e6}
// P5: L1 {0,1,11,12,13} + L2 {0,1,12,13}  V={e0+e12+e13, e0+e1, e10+e11, e11+e12, e12+e13}
// P6: L2 {2..6}          V={e0+e2,..,e4+e6}
// P7: L2 {7..11} + measurement  V={e5+e7,..,e9+e11}
constexpr u32 PV3[5] = {0x040, 0x080, 0x100, 0x200, 0x400};
constexpr u32 PV4[5] = {0x006, 0x00C, 0x018, 0x030, 0x060};
constexpr u32 PV5[5] = {0x3001, 0x0003, 0x0C00, 0x1800, 0x3000};
constexpr u32 PV6[5] = {0x005, 0x00A, 0x014, 0x028, 0x050};
constexpr u32 PV7[5] = {0x0A0, 0x140, 0x280, 0x500, 0xA00};

__host__ __device__ constexpr u32 moff(const u32* v, int r) {
    u32 m = 0;
    for (int i = 0; i < 5; ++i) if ((r >> i) & 1) m ^= v[i];
    return m;
}
// PAR bit r = logical-bit_b at layer L of the register offset m(r):
// sign flip for pair starting at r when (sB ^ PAR_r) == 1.
__host__ __device__ constexpr u32 parmask(const u32* v, int L, int b) {
    u32 pm = 0;
    for (int r = 0; r < 32; ++r)
        pm |= ((mpow(moff(v, r), L) >> b) & 1u) << r;
    return pm;
}
__host__ __device__ constexpr int hbit(int D) {
    int h = 0;
    while (D >> (h + 1)) ++h;
    return 1 << h;
}

// Scalar rotation (R0-proven codegen): n0 = fma(c,a0,-(s*a1)), n1 = fma(c,a1,s*a0).
__device__ __forceinline__ void rot2(float2& a0, float2& a1, float c, float s) {
    float t0x = s * a1.x, t0y = s * a1.y;
    float t1x = s * a0.x, t1y = s * a0.y;
    float n0x = fmaf(c, a0.x, -t0x), n0y = fmaf(c, a0.y, -t0y);
    float n1x = fmaf(c, a1.x,  t1x), n1y = fmaf(c, a1.y,  t1y);
    a0.x = n0x; a0.y = n0y;
    a1.x = n1x; a1.y = n1y;
}

// Generalized butterfly over register XOR-mask D with per-pair sign handling.
// Passing -s swaps the logical roles of (am[r], am[r^D]) exactly.
template<int D, u32 PM>
__device__ __forceinline__ void gateGM(float2 (&am)[32], float c, float s, u32 sB) {
    constexpr int H = hbit(D);
    float sp = sB ? -s : s;
    #pragma unroll
    for (int r = 0; r < 32; ++r)
        if (!(r & H)) {
            if ((PM >> r) & 1) rot2(am[r], am[r ^ D], c, -sp);
            else               rot2(am[r], am[r ^ D], c,  sp);
        }
}

__global__ __launch_bounds__(NT, 2) void qsim_kernel(
    const float* __restrict__ sreal, const float* __restrict__ simag,
    const float* __restrict__ wts,   const float* __restrict__ hw,
    const float* __restrict__ hb,    float* __restrict__ out)
{
    extern __shared__ float smem[];
    float* angC   = smem + 32768;
    float* angS   = angC + 48;
    float* lutLo  = angS + 48;
    float* lutHi  = lutLo + 128;
    float* redbuf = lutHi + 128;
    float2* st2 = (float2*)smem;
    float4* stv = (float4*)smem;

    int tid = threadIdx.x;
    int b   = blockIdx.x;

    // global load, P1 layout: float4 (h<<9)|tid covers p = (h<<11)|(tid<<2)|{0..3}
    const float4* pr = (const float4*)(sreal + (size_t)b * DIM);
    const float4* pi = (const float4*)(simag + (size_t)b * DIM);
    float4 vr[8], vi[8];
    #pragma unroll
    for (int h = 0; h < 8; ++h) {
        vr[h] = pr[(h << 9) | tid];
        vi[h] = pi[(h << 9) | tid];
    }

    // block-uniform setup: summed half-angles (3 RYs/wire/layer compose) + head LUTs
    if (tid < 42) {
        int l = tid / 14, bb = tid % 14, q = 13 - bb;   // bit bb <-> wire 13-bb
        float a = 0.5f * (wts[l * 42 + q] + wts[l * 42 + 14 + q] + wts[l * 42 + 28 + q]);
        angC[l * 16 + bb] = cosf(a);
        angS[l * 16 + bb] = sinf(a);
    } else if (tid >= 64 && tid < 192) {
        int i = tid - 64;           // low 7 index bits -> wires 13..7
        float ssum = 0.f;
        for (int bb = 0; bb < 7; ++bb) if ((i >> bb) & 1) ssum += hw[13 - bb];
        lutLo[i] = ssum;
    } else if (tid >= 192 && tid < 320) {
        int i = tid - 192;          // high 7 index bits -> wires 6..0
        float ssum = 0.f;
        for (int bb = 0; bb < 7; ++bb) if ((i >> bb) & 1) ssum += hw[6 - bb];
        lutHi[i] = ssum;
    }

    float2 am[32];
    #pragma unroll
    for (int h = 0; h < 8; ++h) {
        am[h * 4 + 0] = make_float2(vr[h].x, vi[h].x);
        am[h * 4 + 1] = make_float2(vr[h].y, vi[h].y);
        am[h * 4 + 2] = make_float2(vr[h].z, vi[h].z);
        am[h * 4 + 3] = make_float2(vr[h].w, vi[h].w);
    }

    __syncthreads();
    float W0  = lutLo[127] + lutHi[127];
    float acc = 0.f;

    // ================= P1: L0 gates {0,1,11,12,13}; b128 write =================
    {
        gateGM< 1, 0>(am, angC[ 0], angS[ 0], 0);
        gateGM< 2, 0>(am, angC[ 1], angS[ 1], 0);
        gateGM< 4, 0>(am, angC[11], angS[11], 0);
        gateGM< 8, 0>(am, angC[12], angS[12], 0);
        gateGM<16, 0>(am, angC[13], angS[13], 0);
        u32 base = swzN((u32)tid << 2);
        bool sw = (((tid >> 2) ^ (tid >> 3)) & 1) != 0;   // slot bit0 flips with y4^y5
        #pragma unroll
        for (int h = 0; h < 8; ++h)
            #pragma unroll
            for (int m = 0; m < 2; ++m) {
                u32 idx = (base ^ swzN(((u32)h << 11) | ((u32)m << 1))) >> 1;
                int r = h * 4 + m * 2;
                float2 a0 = am[r], a1 = am[r + 1];
                stv[idx] = sw ? make_float4(a1.x, a1.y, a0.x, a0.y)
                              : make_float4(a0.x, a0.y, a1.x, a1.y);
            }
        __syncthreads();
    }

    // ================= P2: L0 gates {2,3,4,5}; b128 r/w =================
    {
        u32 yb = (((u32)tid & 1u) << 1) | (((u32)tid >> 1) << 6);  // tid0->y1, tid1..8->y6..y13
        u32 base = swzN(yb);
        #pragma unroll
        for (int h = 0; h < 16; ++h) {
            u32 idx = (base ^ swzN((u32)h << 2)) >> 1;
            float4 v = stv[idx];
            if (((h >> 2) ^ (h >> 3)) & 1) {
                am[h * 2 + 1] = make_float2(v.x, v.y);
                am[h * 2]     = make_float2(v.z, v.w);
            } else {
                am[h * 2]     = make_float2(v.x, v.y);
                am[h * 2 + 1] = make_float2(v.z, v.w);
            }
        }
        gateGM< 2, 0>(am, angC[2], angS[2], 0);
        gateGM< 4, 0>(am, angC[3], angS[3], 0);
        gateGM< 8, 0>(am, angC[4], angS[4], 0);
        gateGM<16, 0>(am, angC[5], angS[5], 0);
        #pragma unroll
        for (int h = 0; h < 16; ++h) {
            u32 idx = (base ^ swzN((u32)h << 2)) >> 1;
            float2 a0 = am[h * 2], a1 = am[h * 2 + 1];
            if (((h >> 2) ^ (h >> 3)) & 1) stv[idx] = make_float4(a1.x, a1.y, a0.x, a0.y);
            else                           stv[idx] = make_float4(a0.x, a0.y, a1.x, a1.y);
        }
        __syncthreads();
    }

    // ================= P3: L0 {6..10} + L1 {7..10} =================
    {
        u32 B = ((u32)tid & 63u) | (((u32)tid >> 6) << 11);
        u32 base = swzN(B);
        #pragma unroll
        for (int j = 0; j < 32; ++j) am[j] = st2[base ^ swzN((u32)j << 6)];
        gateGM< 1, 0>(am, angC[ 6], angS[ 6], 0);
        gateGM< 2, 0>(am, angC[ 7], angS[ 7], 0);
        gateGM< 4, 0>(am, angC[ 8], angS[ 8], 0);
        gateGM< 8, 0>(am, angC[ 9], angS[ 9], 0);
        gateGM<16, 0>(am, angC[10], angS[10], 0);
        u32 z1 = mmap(B);
        gateGM< 3, parmask(PV3, 1,  7)>(am, angC[16 +  7], angS[16 +  7], (z1 >>  7) & 1u);
        gateGM< 6, parmask(PV3, 1,  8)>(am, angC[16 +  8], angS[16 +  8], (z1 >>  8) & 1u);
        gateGM<12, parmask(PV3, 1,  9)>(am, angC[16 +  9], angS[16 +  9], (z1 >>  9) & 1u);
        gateGM<24, parmask(PV3, 1, 10)>(am, angC[16 + 10], angS[16 + 10], (z1 >> 10) & 1u);
        #pragma unroll
        for (int j = 0; j < 32; ++j) st2[base ^ swzN((u32)j << 6)] = am[j];
        __syncthreads();
    }

    // ================= P4: L1 {2..6} =================
    {
        u32 B = ((u32)tid & 3u) | (((u32)tid >> 2) << 7);   // tid0,1->y0,y1; tid2..8->y7..y13
        u32 base = swzN(B);
        #pragma unroll
        for (int r = 0; r < 32; ++r) am[r] = st2[base ^ swzN(moff(PV4, r))];
        u32 z1 = mmap(B);
        gateGM< 1, parmask(PV4, 1, 2)>(am, angC[16 + 2], angS[16 + 2], (z1 >> 2) & 1u);
        gateGM< 2, parmask(PV4, 1, 3)>(am, angC[16 + 3], angS[16 + 3], (z1 >> 3) & 1u);
        gateGM< 4, parmask(PV4, 1, 4)>(am, angC[16 + 4], angS[16 + 4], (z1 >> 4) & 1u);
        gateGM< 8, parmask(PV4, 1, 5)>(am, angC[16 + 5], angS[16 + 5], (z1 >> 5) & 1u);
        gateGM<16, parmask(PV4, 1, 6)>(am, angC[16 + 6], angS[16 + 6], (z1 >> 6) & 1u);
        #pragma unroll
        for (int r = 0; r < 32; ++r) st2[base ^ swzN(moff(PV4, r))] = am[r];
        __syncthreads();
    }

    // ================= P5: L1 {0,1,11,12,13} + L2 {0,1,12,13} =================
    {
        u32 B = (((u32)tid & 0xFFu) << 2) | (((u32)tid >> 8) << 13);  // tid0..7->y2..y9; tid8->y13
        u32 base = swzN(B);
        #pragma unroll
        for (int r = 0; r < 32; ++r) am[r] = st2[base ^ swzN(moff(PV5, r))];
        u32 z1 = mmap(B), z2 = mmap(z1);
        gateGM< 1, parmask(PV5, 1,  0)>(am, angC[16 +  0], angS[16 +  0], (z1 >>  0) & 1u);
        gateGM< 2, parmask(PV5, 1,  1)>(am, angC[16 +  1], angS[16 +  1], (z1 >>  1) & 1u);
        gateGM< 4, parmask(PV5, 1, 11)>(am, angC[16 + 11], angS[16 + 11], (z1 >> 11) & 1u);
        gateGM< 8, parmask(PV5, 1, 12)>(am, angC[16 + 12], angS[16 + 12], (z1 >> 12) & 1u);
        gateGM<16, parmask(PV5, 1, 13)>(am, angC[16 + 13], angS[16 + 13], (z1 >> 13) & 1u);
        // L2: strides in v-basis: D(0)=25, D(1)=3, D(12)=12, D(13)=24
        gateGM<25, parmask(PV5, 2,  0)>(am, angC[32 +  0], angS[32 +  0], (z2 >>  0) & 1u);
        gateGM< 3, parmask(PV5, 2,  1)>(am, angC[32 +  1], angS[32 +  1], (z2 >>  1) & 1u);
        gateGM<12, parmask(PV5, 2, 12)>(am, angC[32 + 12], angS[32 + 12], (z2 >> 12) & 1u);
        gateGM<24, parmask(PV5, 2, 13)>(am, angC[32 + 13], angS[32 + 13], (z2 >> 13) & 1u);
        #pragma unroll
        for (int r = 0; r < 32; ++r) st2[base ^ swzN(moff(PV5, r))] = am[r];
        __syncthreads();
    }

    // ================= P6: L2 {2..6} =================
    {
        u32 B = ((u32)tid & 3u) | (((u32)tid >> 2) << 7);
        u32 base = swzN(B);
        #pragma unroll
        for (int r = 0; r < 32; ++r) am[r] = st2[base ^ swzN(moff(PV6, r))];
        u32 z2 = mpow(B, 2);
        gateGM< 1, parmask(PV6, 2, 2)>(am, angC[32 + 2], angS[32 + 2], (z2 >> 2) & 1u);
        gateGM< 2, parmask(PV6, 2, 3)>(am, angC[32 + 3], angS[32 + 3], (z2 >> 3) & 1u);
        gateGM< 4, parmask(PV6, 2, 4)>(am, angC[32 + 4], angS[32 + 4], (z2 >> 4) & 1u);
        gateGM< 8, parmask(PV6, 2, 5)>(am, angC[32 + 5], angS[32 + 5], (z2 >> 5) & 1u);
        gateGM<16, parmask(PV6, 2, 6)>(am, angC[32 + 6], angS[32 + 6], (z2 >> 6) & 1u);
        #pragma unroll
        for (int r = 0; r < 32; ++r) st2[base ^ swzN(moff(PV6, r))] = am[r];
        __syncthreads();
    }

    // ================= P7: L2 {7..11} + fused measurement (no write) =================
    {
        u32 B = ((u32)tid & 0x7Fu) | (((u32)tid >> 7) << 12);  // tid0..6->y0..y6; tid7,8->y12,y13
        u32 base = swzN(B);
        #pragma unroll
        for (int r = 0; r < 32; ++r) am[r] = st2[base ^ swzN(moff(PV7, r))];
        u32 z2 = mpow(B, 2);
        gateGM< 1, parmask(PV7, 2,  7)>(am, angC[32 +  7], angS[32 +  7], (z2 >>  7) & 1u);
        gateGM< 2, parmask(PV7, 2,  8)>(am, angC[32 +  8], angS[32 +  8], (z2 >>  8) & 1u);
        gateGM< 4, parmask(PV7, 2,  9)>(am, angC[32 +  9], angS[32 +  9], (z2 >>  9) & 1u);
        gateGM< 8, parmask(PV7, 2, 10)>(am, angC[32 + 10], angS[32 + 10], (z2 >> 10) & 1u);
        gateGM<16, parmask(PV7, 2, 11)>(am, angC[32 + 11], angS[32 + 11], (z2 >> 11) & 1u);
        // final basis index after 3rd ring: w = mmap^3(p)
        u32 wB = mmap(z2);
        #pragma unroll
        for (int r = 0; r < 32; ++r) {
            u32 w = wB ^ mpow(moff(PV7, r), 3);
            float p  = fmaf(am[r].x, am[r].x, am[r].y * am[r].y);
            float wv = W0 - 2.0f * (lutLo[w & 127u] + lutHi[w >> 7]);
            acc = fmaf(wv, p, acc);
        }
    }

    // block reduction
    #pragma unroll
    for (int off = 32; off > 0; off >>= 1) acc += __shfl_xor(acc, off, 64);
    if ((tid & 63) == 0) redbuf[tid >> 6] = acc;
    __syncthreads();
    if (tid == 0) {
        float tot = hb[0];
        #pragma unroll
        for (int i = 0; i < 8; ++i) tot += redbuf[i];
        out[b] = tot;
    }
}

extern "C" void kernel_launch(void* const* d_in, const int* in_sizes, int n_in,
                              void* d_out, int out_size, void* d_ws, size_t ws_size,
                              hipStream_t stream)
{
    const float* sreal = (const float*)d_in[0];
    const float* simag = (const float*)d_in[1];
    const float* wts   = (const float*)d_in[2];
    const float* hw    = (const float*)d_in[3];
    const float* hb    = (const float*)d_in[4];
    float* out = (float*)d_out;

    int batch = in_sizes[0] / DIM;
    size_t smem_bytes = (32768 + 48 + 48 + 128 + 128 + 16) * sizeof(float);  // 132.5 KB < 160 KB

    (void)hipFuncSetAttribute((const void*)qsim_kernel,
                              hipFuncAttributeMaxDynamicSharedMemorySize, (int)smem_bytes);
    qsim_kernel<<<dim3(batch), dim3(NT), smem_bytes, stream>>>(sreal, simag, wts, hw, hb, out);
}